// Round 1
// baseline (197.739 us; speedup 1.0000x reference)
//
#include <hip/hip_runtime.h>

// 5x5 normalized box blur, REFLECT_101, fp32, NCHW 32x3x512x512.
// Register-only separable filter: no LDS.
// Each thread: 4 output columns (float4) x 16 output rows (vertical running sum).
// Block: 256 threads = 16 tx (64 cols) x 16 ty (256 rows). Grid: 8 x 2 x 96.

#define WID 512
#define HEI 512
#define RPT 16   // rows per thread
#define TXN 16   // threads in x -> 64 cols/block
#define TYN 16   // threads in y -> 256 rows/block

__device__ __forceinline__ float4 add4(float4 a, float4 b) {
    return make_float4(a.x + b.x, a.y + b.y, a.z + b.z, a.w + b.w);
}
__device__ __forceinline__ float4 sub4(float4 a, float4 b) {
    return make_float4(a.x - b.x, a.y - b.y, a.z - b.z, a.w - b.w);
}

__global__ __launch_bounds__(256) void smooth_box5_kernel(
    const float* __restrict__ in, float* __restrict__ out)
{
    const int tid = threadIdx.x;
    const int tx  = tid & (TXN - 1);
    const int ty  = tid >> 4;
    const int c   = blockIdx.x * (TXN * 4) + tx * 4;
    const int r0  = blockIdx.y * (TYN * RPT) + ty * RPT;
    const long long plane = blockIdx.z;

    const float* __restrict__ ip = in  + plane * (long long)(HEI * WID);
    float*       __restrict__ op = out + plane * (long long)(HEI * WID);

    const bool leftE  = (c == 0);
    const bool rightE = (c == WID - 4);

    // Horizontal 5-tap sums (unnormalized) for 4 columns of one input row.
    auto hsum = [&](int gy) -> float4 {
        // REFLECT_101 row index
        gy = (gy < 0) ? -gy : ((gy >= HEI) ? (2 * HEI - 2 - gy) : gy);
        const float* row = ip + gy * WID;
        float4 m = *reinterpret_cast<const float4*>(row + c);       // 16B aligned
        float2 l, r;
        if (leftE)  l = make_float2(m.z, m.y);                      // cols -2,-1 -> 2,1
        else        l = *reinterpret_cast<const float2*>(row + c - 2);  // 8B aligned
        if (rightE) r = make_float2(m.z, m.y);                      // cols 512,513 -> 510,509
        else        r = *reinterpret_cast<const float2*>(row + c + 4);  // 8B aligned
        float t  = m.y + m.z;
        float u  = m.x + t;        // x+y+z
        float v  = t + m.w;        // y+z+w
        float s4 = u + m.w;        // x+y+z+w
        float4 h;
        h.x = (l.x + l.y) + u;     // c-2 .. c+2
        h.y = l.y + s4;            // c-1 .. c+3
        h.z = s4 + r.x;            // c   .. c+4
        h.w = v + (r.x + r.y);     // c+1 .. c+5
        return h;
    };

    // Ring of 5 horizontal-sum rows; slot = seq % 5, seq j holds input row r0-2+j.
    float4 h[5];
    h[0] = hsum(r0 - 2);
    h[1] = hsum(r0 - 1);
    h[2] = hsum(r0);
    h[3] = hsum(r0 + 1);
    float4 vs = add4(add4(h[0], h[1]), add4(h[2], h[3]));

    float* orow = op + r0 * WID + c;

    #pragma unroll
    for (int k = 0; k < RPT; ++k) {
        float4 hn = hsum(r0 + 2 + k);
        h[(4 + k) % 5] = hn;           // static index after full unroll
        vs = add4(vs, hn);             // window rows [r0-2+k, r0+2+k]
        float4 o = make_float4(vs.x * 0.04f, vs.y * 0.04f,
                               vs.z * 0.04f, vs.w * 0.04f);
        *reinterpret_cast<float4*>(orow) = o;
        vs = sub4(vs, h[k % 5]);       // drop oldest row (r0-2+k)
        orow += WID;
    }
}

extern "C" void kernel_launch(void* const* d_in, const int* in_sizes, int n_in,
                              void* d_out, int out_size, void* d_ws, size_t ws_size,
                              hipStream_t stream) {
    const float* img = (const float*)d_in[0];
    float* out = (float*)d_out;
    // Shapes fixed by the reference: (32, 3, 512, 512), w = 5.
    const int B = 32, C = 3;
    dim3 grid(WID / (TXN * 4), HEI / (TYN * RPT), B * C);  // 8 x 2 x 96
    dim3 block(256);
    smooth_box5_kernel<<<grid, block, 0, stream>>>(img, out);
}

// Round 2
// 189.479 us; speedup vs baseline: 1.0436x; 1.0436x over previous
//
#include <hip/hip_runtime.h>

// 5x5 normalized box blur, REFLECT_101, fp32, NCHW 32x3x512x512.
// Full-row waves: each wave = 64 lanes x 8 cols = one whole 512-col row.
// Every global load/store is a dense contiguous 2KB wave transaction.
// Horizontal halo via __shfl from neighbor lanes (no halo loads).
// Vertical 5-tap as register ring + running sum, 8 rows per thread.
// Block: 4 waves -> 32-row full-width strip. Grid: 16 x 96.

#define WID 512
#define HEI 512
#define RPT 8                 // rows per thread
#define STRIP (4 * RPT)       // 32 rows per block (4 waves)

__global__ __launch_bounds__(256) void smooth_box5_kernel(
    const float* __restrict__ in, float* __restrict__ out)
{
    const int tid  = threadIdx.x;
    const int lane = tid & 63;
    const int wv   = tid >> 6;              // wave id 0..3
    const int c    = lane << 3;             // 8 cols per lane, wave covers 512
    const int r0   = blockIdx.x * STRIP + wv * RPT;
    const long long plane = blockIdx.y;

    const float* __restrict__ ip = in  + plane * (long long)(HEI * WID);
    float*       __restrict__ op = out + plane * (long long)(HEI * WID);

    const bool Ledge = (lane == 0);
    const bool Redge = (lane == 63);

    // Load one full input row segment (8 cols) as two float4s. REFLECT_101 rows.
    auto loadraw = [&](int gy, float4& m0, float4& m1) {
        gy = (gy < 0) ? -gy : ((gy >= HEI) ? (2 * HEI - 2 - gy) : gy);
        const float* row = ip + gy * WID + c;
        m0 = *reinterpret_cast<const float4*>(row);
        m1 = *reinterpret_cast<const float4*>(row + 4);
    };

    // Horizontal 5-tap sums (unnormalized) for this lane's 8 columns.
    // Halo cols c-2,c-1 / c+8,c+9 come from neighbor lanes via shfl.
    auto hsum = [&](const float4 m0, const float4 m1, float h[8]) {
        float lx = __shfl_up(m1.z, 1);      // lane-1 col (c-8)+6 = c-2
        float ly = __shfl_up(m1.w, 1);      // c-1
        float rx = __shfl_down(m0.x, 1);    // lane+1 col c+8
        float ry = __shfl_down(m0.y, 1);    // c+9
        if (Ledge) { lx = m0.z; ly = m0.y; }    // cols -2,-1 -> 2,1
        if (Redge) { rx = m1.z; ry = m1.y; }    // cols 512,513 -> 510,509
        float a[12] = { lx, ly, m0.x, m0.y, m0.z, m0.w,
                        m1.x, m1.y, m1.z, m1.w, rx, ry };
        float t[11];
        #pragma unroll
        for (int j = 0; j < 11; ++j) t[j] = a[j] + a[j + 1];
        #pragma unroll
        for (int j = 0; j < 8; ++j) h[j] = t[j] + t[j + 2] + a[j + 4];
    };

    // Ring of 5 h-rows; slot j initially holds input row r0-2+j.
    float h[5][8];
    float vs[8];
    float4 cm0, cm1, nm0, nm1;

    loadraw(r0 - 2, cm0, cm1);
    loadraw(r0 - 1, nm0, nm1);
    hsum(cm0, cm1, h[0]);
    cm0 = nm0; cm1 = nm1; loadraw(r0,     nm0, nm1);
    hsum(cm0, cm1, h[1]);
    cm0 = nm0; cm1 = nm1; loadraw(r0 + 1, nm0, nm1);
    hsum(cm0, cm1, h[2]);
    cm0 = nm0; cm1 = nm1; loadraw(r0 + 2, nm0, nm1);
    hsum(cm0, cm1, h[3]);

    #pragma unroll
    for (int j = 0; j < 8; ++j)
        vs[j] = h[0][j] + h[1][j] + h[2][j] + h[3][j];

    float* orow = op + (long long)r0 * WID + c;

    #pragma unroll
    for (int k = 0; k < RPT; ++k) {
        cm0 = nm0; cm1 = nm1;
        if (k < RPT - 1) loadraw(r0 + 3 + k, nm0, nm1);   // prefetch next row
        float hn[8];
        hsum(cm0, cm1, hn);                               // row r0+2+k
        #pragma unroll
        for (int j = 0; j < 8; ++j) h[(4 + k) % 5][j] = hn[j];
        float o[8];
        #pragma unroll
        for (int j = 0; j < 8; ++j) {
            vs[j] += hn[j];
            o[j] = vs[j] * 0.04f;
        }
        *reinterpret_cast<float4*>(orow)     = make_float4(o[0], o[1], o[2], o[3]);
        *reinterpret_cast<float4*>(orow + 4) = make_float4(o[4], o[5], o[6], o[7]);
        #pragma unroll
        for (int j = 0; j < 8; ++j) vs[j] -= h[k % 5][j]; // drop row r0-2+k
        orow += WID;
    }
}

extern "C" void kernel_launch(void* const* d_in, const int* in_sizes, int n_in,
                              void* d_out, int out_size, void* d_ws, size_t ws_size,
                              hipStream_t stream) {
    const float* img = (const float*)d_in[0];
    float* out = (float*)d_out;
    // Shapes fixed by the reference: (32, 3, 512, 512), w = 5.
    const int B = 32, C = 3;
    dim3 grid(HEI / STRIP, B * C);   // 16 x 96 = 1536 blocks
    dim3 block(256);
    smooth_box5_kernel<<<grid, block, 0, stream>>>(img, out);
}